// Round 1
// baseline (1185.432 us; speedup 1.0000x reference)
//
#include <hip/hip_runtime.h>
#include <hip/hip_bf16.h>
#include <math.h>

// Problem constants
constexpr int B_  = 4;
constexpr int T_  = 1024;
constexpr int D_  = 768;
constexpr int L_  = 4;
constexpr int V_  = 50257;
constexpr int DFF_ = 3072;

// ---------------------------------------------------------------------------
// kwm[d'] = mean over d of kw[0][d'][d]   (only layer 0 needed: layers 1-3
// have uniform softmax regardless of scores). One wave per row.
__global__ void kwm_kernel(const float* __restrict__ kw, float* __restrict__ kwm) {
    int wave = (blockIdx.x * blockDim.x + threadIdx.x) >> 6;  // 0..D-1
    int lane = threadIdx.x & 63;
    if (wave >= D_) return;
    const float* row = kw + (size_t)wave * D_;
    float s = 0.f;
    for (int j = lane; j < D_; j += 64) s += row[j];
    for (int m = 32; m; m >>= 1) s += __shfl_xor(s, m);
    if (lane == 0) kwm[wave] = s * (1.0f / D_);
}

// ---------------------------------------------------------------------------
// Initialize all accumulator buffers (ws is poisoned 0xAA every call):
//   ctx[l][b][n] = vb[l][n]; fc = 0; xn = 0; xw = 0.
__global__ void init_kernel(const float* __restrict__ vb, float* __restrict__ ctx,
                            float* __restrict__ fc, float* __restrict__ xn,
                            float* __restrict__ xw) {
    int i = blockIdx.x * 256 + threadIdx.x;
    const int N_CTX = L_ * B_ * D_;      // 12288
    const int N_FC  = L_ * B_ * DFF_;    // 49152
    const int N_XN  = L_ * B_ * D_;      // 12288
    if (i < N_CTX) {
        int l = i / (B_ * D_);
        int n = i % D_;
        ctx[i] = vb[l * D_ + n];
    } else if (i < N_CTX + N_FC) {
        fc[i - N_CTX] = 0.f;
    } else if (i < N_CTX + N_FC + N_XN) {
        xn[i - N_CTX - N_FC] = 0.f;
    } else {
        int j = i - (N_CTX + N_FC + N_XN);
        if (j < B_ * D_) xw[j] = 0.f;
    }
}

// ---------------------------------------------------------------------------
// kmean[b,t] = (wte[idx[b,t]] + wpe[t]) . kwm   — one wave per token.
__global__ void embed_kmean(const int* __restrict__ idx, const float* __restrict__ wte,
                            const float* __restrict__ wpe, const float* __restrict__ kwm,
                            float* __restrict__ kmean) {
    int rid = (blockIdx.x * 256 + threadIdx.x) >> 6;  // 0..B*T-1
    int lane = threadIdx.x & 63;
    int t = rid & (T_ - 1);
    int tok = idx[rid];
    const float* wrow = wte + (size_t)tok * D_;
    const float* prow = wpe + (size_t)t * D_;
    float s = 0.f;
    for (int j = lane; j < D_; j += 64) s += (wrow[j] + prow[j]) * kwm[j];
    for (int m = 32; m; m >>= 1) s += __shfl_xor(s, m);
    if (lane == 0) kmean[rid] = s;
}

// ---------------------------------------------------------------------------
// Layer-0 softmax over T per batch: w = softmax(cos(kmean + mean(kb0))).
__global__ void softmax_kernel(const float* __restrict__ kmean, const float* __restrict__ kb,
                               float* __restrict__ w) {
    __shared__ float red[256];
    int b = blockIdx.x, tid = threadIdx.x;
    // kbm = mean(kb layer 0)
    float s = 0.f;
    for (int j = tid; j < D_; j += 256) s += kb[j];
    red[tid] = s; __syncthreads();
    for (int off = 128; off; off >>= 1) { if (tid < off) red[tid] += red[tid + off]; __syncthreads(); }
    float kbm = red[0] * (1.0f / D_);
    __syncthreads();

    float sc[4]; float mx = -1e30f;
    for (int i = 0; i < 4; i++) {
        sc[i] = cosf(kmean[b * T_ + tid + i * 256] + kbm);
        mx = fmaxf(mx, sc[i]);
    }
    red[tid] = mx; __syncthreads();
    for (int off = 128; off; off >>= 1) { if (tid < off) red[tid] = fmaxf(red[tid], red[tid + off]); __syncthreads(); }
    mx = red[0]; __syncthreads();

    float es[4]; float sum = 0.f;
    for (int i = 0; i < 4; i++) { es[i] = expf(sc[i] - mx); sum += es[i]; }
    red[tid] = sum; __syncthreads();
    for (int off = 128; off; off >>= 1) { if (tid < off) red[tid] += red[tid + off]; __syncthreads(); }
    float inv = 1.0f / red[0];
    for (int i = 0; i < 4; i++) w[b * T_ + tid + i * 256] = es[i] * inv;
}

// ---------------------------------------------------------------------------
// xw[b,d] += sum over t-chunk of w[b,t]*(wte[idx[b,t],d]+wpe[t,d]).
// grid (D/256, T/128, B)
__global__ void xw_kernel(const int* __restrict__ idx, const float* __restrict__ wte,
                          const float* __restrict__ wpe, const float* __restrict__ w,
                          float* __restrict__ xw) {
    int d = blockIdx.x * 256 + threadIdx.x;
    int b = blockIdx.z;
    int t0 = blockIdx.y * 128;
    float acc = 0.f;
    for (int t = t0; t < t0 + 128; t++) {
        float wt = w[b * T_ + t];
        int tok = idx[b * T_ + t];
        acc += wt * (wte[(size_t)tok * D_ + d] + wpe[t * D_ + d]);
    }
    atomicAdd(&xw[b * D_ + d], acc);
}

// ---------------------------------------------------------------------------
// y[b][n] += sum_{k in 64-chunk} x[b][k]*W[k][n]  (4-row matvec, K-split atomics).
// GELU: apply exact gelu to x on load (used for the c_proj matvec).
template <bool GELU>
__global__ void matvec_acc(const float* __restrict__ x, const float* __restrict__ W,
                           float* __restrict__ y, int K, int N) {
    __shared__ float xs[4][64];
    int n = blockIdx.x * 256 + threadIdx.x;
    int k0 = blockIdx.y * 64;
    {
        int b = threadIdx.x >> 6, kk = threadIdx.x & 63;
        float v = x[b * K + k0 + kk];
        if (GELU) v = 0.5f * v * (1.0f + erff(v * 0.70710678118654752f));
        xs[b][kk] = v;
    }
    __syncthreads();
    float a0 = 0, a1 = 0, a2 = 0, a3 = 0;
    for (int kk = 0; kk < 64; kk++) {
        float wv = W[(size_t)(k0 + kk) * N + n];
        a0 += xs[0][kk] * wv;
        a1 += xs[1][kk] * wv;
        a2 += xs[2][kk] * wv;
        a3 += xs[3][kk] * wv;
    }
    atomicAdd(&y[0 * N + n], a0);
    atomicAdd(&y[1 * N + n], a1);
    atomicAdd(&y[2 * N + n], a2);
    atomicAdd(&y[3 * N + n], a3);
}

// ---------------------------------------------------------------------------
// Final layernorm on (B, D): xln = (x-mu)*rsqrt(var+1e-5)*ln_w
__global__ void ln_kernel(const float* __restrict__ x, const float* __restrict__ ln_w,
                          float* __restrict__ xln) {
    __shared__ float red[256];
    int b = blockIdx.x, tid = threadIdx.x;
    float v[3];
    float s = 0.f;
    for (int i = 0; i < 3; i++) { v[i] = x[b * D_ + tid + i * 256]; s += v[i]; }
    red[tid] = s; __syncthreads();
    for (int off = 128; off; off >>= 1) { if (tid < off) red[tid] += red[tid + off]; __syncthreads(); }
    float mu = red[0] * (1.0f / D_); __syncthreads();
    float vs = 0.f;
    for (int i = 0; i < 3; i++) { float c = v[i] - mu; vs += c * c; }
    red[tid] = vs; __syncthreads();
    for (int off = 128; off; off >>= 1) { if (tid < off) red[tid] += red[tid + off]; __syncthreads(); }
    float inv = rsqrtf(red[0] * (1.0f / D_) + 1e-5f);
    for (int i = 0; i < 3; i++) {
        int d2 = tid + i * 256;
        xln[b * D_ + d2] = (v[i] - mu) * inv * ln_w[d2];
    }
}

// ---------------------------------------------------------------------------
// logits_row[b][v] = xln[b] . wte[v]  — one wave per vocab row, float4 loads.
__global__ void lmhead_kernel(const float* __restrict__ wte, const float* __restrict__ xln,
                              float* __restrict__ out /* B x V */) {
    __shared__ float xs[B_ * D_];
    for (int i = threadIdx.x; i < B_ * D_; i += 256) xs[i] = xln[i];
    __syncthreads();
    int v = blockIdx.x * 4 + (threadIdx.x >> 6);
    int lane = threadIdx.x & 63;
    if (v >= V_) return;
    const float* row = wte + (size_t)v * D_;
    float a0 = 0, a1 = 0, a2 = 0, a3 = 0;
    for (int it = 0; it < 3; it++) {
        int j = it * 256 + lane * 4;
        float4 wv = *(const float4*)(row + j);
        a0 += wv.x * xs[0 * D_ + j] + wv.y * xs[0 * D_ + j + 1] + wv.z * xs[0 * D_ + j + 2] + wv.w * xs[0 * D_ + j + 3];
        a1 += wv.x * xs[1 * D_ + j] + wv.y * xs[1 * D_ + j + 1] + wv.z * xs[1 * D_ + j + 2] + wv.w * xs[1 * D_ + j + 3];
        a2 += wv.x * xs[2 * D_ + j] + wv.y * xs[2 * D_ + j + 1] + wv.z * xs[2 * D_ + j + 2] + wv.w * xs[2 * D_ + j + 3];
        a3 += wv.x * xs[3 * D_ + j] + wv.y * xs[3 * D_ + j + 1] + wv.z * xs[3 * D_ + j + 2] + wv.w * xs[3 * D_ + j + 3];
    }
    for (int m = 32; m; m >>= 1) {
        a0 += __shfl_xor(a0, m); a1 += __shfl_xor(a1, m);
        a2 += __shfl_xor(a2, m); a3 += __shfl_xor(a3, m);
    }
    if (lane == 0) {
        out[0 * V_ + v] = a0; out[1 * V_ + v] = a1;
        out[2 * V_ + v] = a2; out[3 * V_ + v] = a3;
    }
}

// ---------------------------------------------------------------------------
// Broadcast logits_row (B,V) -> out (B,T,V). One block per (b,t) row.
__global__ void bcast_kernel(const float* __restrict__ rows, float* __restrict__ out) {
    long long rid = blockIdx.x;  // b*T + t
    int b = (int)(rid >> 10);
    const float* src = rows + (long long)b * V_;
    float* dst = out + rid * V_;
    size_t start = (size_t)rid * V_;
    int head = (int)((4 - (start & 3)) & 3);
    int tid = threadIdx.x;
    if (tid < head) dst[tid] = src[tid];
    int n4 = (V_ - head) >> 2;
    const float* s2 = src + head;
    float4* d4 = (float4*)(dst + head);
    for (int j = tid; j < n4; j += 256) {
        float4 val;
        val.x = s2[4 * j]; val.y = s2[4 * j + 1];
        val.z = s2[4 * j + 2]; val.w = s2[4 * j + 3];
        d4[j] = val;
    }
    int tail0 = head + n4 * 4;
    int rem = V_ - tail0;
    if (tid < rem) dst[tail0 + tid] = src[tail0 + tid];
}

// ---------------------------------------------------------------------------
extern "C" void kernel_launch(void* const* d_in, const int* in_sizes, int n_in,
                              void* d_out, int out_size, void* d_ws, size_t ws_size,
                              hipStream_t stream) {
    const int*   idx  = (const int*)d_in[0];
    const float* wte  = (const float*)d_in[1];
    const float* wpe  = (const float*)d_in[2];
    const float* ln_w = (const float*)d_in[3];
    // d_in[4]=qw, d_in[5]=qb: dead (score is independent of Q) — never read.
    const float* kw   = (const float*)d_in[6];
    const float* kb   = (const float*)d_in[7];
    const float* vw   = (const float*)d_in[8];
    const float* vb   = (const float*)d_in[9];
    const float* fcw  = (const float*)d_in[10];
    const float* pww  = (const float*)d_in[11];
    float* out = (float*)d_out;

    float* ws    = (float*)d_ws;
    float* kwm   = ws;                       // D
    float* kmean = kwm + D_;                 // B*T
    float* wsm   = kmean + B_ * T_;          // B*T
    float* xw    = wsm + B_ * T_;            // B*D
    float* ctx   = xw + B_ * D_;             // L*B*D
    float* fc    = ctx + L_ * B_ * D_;       // L*B*DFF
    float* xn    = fc + L_ * B_ * DFF_;      // L*B*D
    float* xln   = xn + L_ * B_ * D_;        // B*D
    float* lrow  = xln + B_ * D_;            // B*V

    hipLaunchKernelGGL(kwm_kernel, dim3(192), dim3(256), 0, stream, kw, kwm);
    hipLaunchKernelGGL(init_kernel, dim3(300), dim3(256), 0, stream, vb, ctx, fc, xn, xw);
    hipLaunchKernelGGL(embed_kmean, dim3(1024), dim3(256), 0, stream, idx, wte, wpe, kwm, kmean);
    hipLaunchKernelGGL(softmax_kernel, dim3(4), dim3(256), 0, stream, kmean, kb, wsm);
    hipLaunchKernelGGL(xw_kernel, dim3(3, 8, 4), dim3(256), 0, stream, idx, wte, wpe, wsm, xw);

    for (int l = 0; l < L_; l++) {
        const float* xin = (l == 0) ? xw : (xn + (l - 1) * B_ * D_);
        // ctx_l = xin @ vw_l (+vb via init)
        hipLaunchKernelGGL((matvec_acc<false>), dim3(3, 12), dim3(256), 0, stream,
                           xin, vw + (size_t)l * D_ * D_, ctx + l * B_ * D_, D_, D_);
        // fc_l = ctx_l @ fcw_l
        hipLaunchKernelGGL((matvec_acc<false>), dim3(12, 12), dim3(256), 0, stream,
                           ctx + l * B_ * D_, fcw + (size_t)l * D_ * DFF_, fc + l * B_ * DFF_, D_, DFF_);
        // xn_l = gelu(fc_l) @ pw_l
        hipLaunchKernelGGL((matvec_acc<true>), dim3(3, 48), dim3(256), 0, stream,
                           fc + l * B_ * DFF_, pww + (size_t)l * DFF_ * D_, xn + l * B_ * D_, DFF_, D_);
    }

    hipLaunchKernelGGL(ln_kernel, dim3(B_), dim3(256), 0, stream, xn + 3 * B_ * D_, ln_w, xln);
    hipLaunchKernelGGL(lmhead_kernel, dim3((V_ + 3) / 4), dim3(256), 0, stream, wte, xln, lrow);
    hipLaunchKernelGGL(bcast_kernel, dim3(B_ * T_), dim3(256), 0, stream, lrow, out);
}